// Round 23
// baseline (44.048 us; speedup 1.0000x reference)
//
#include <hip/hip_runtime.h>
#include <math.h>

// Problem constants (from reference): N=50000, F=64, E=800000, C=32
#define NF 64
#define NC 32
#define BN_EPS 1e-3f

#define BSHIFT 6                 // 64 receiver-nodes per bucket
#define BNODES 64
#define NBP 800                  // padded bucket count (>= 782)
#define NBIN 512                 // bin blocks / chunks
#define CHUNK_STRIDE 1600        // u32 slots per bin chunk (>= 1564)
#define CAPR 1408                // max records per bucket (mean 1023, +12 sigma)

typedef _Float16 v8h __attribute__((ext_vector_type(8)));
typedef float    v4f __attribute__((ext_vector_type(4)));

// ---------------------------------------------------------------------------
// Fused kernel A. blockIdx [0,NBIN) = bin, [NBIN, NBIN+TB) = transform.
// (Frozen R22: MFMA transform, paired loads, row-major descriptor table.)
// ---------------------------------------------------------------------------
__global__ __launch_bounds__(256) void prep_kernel(
    const float* __restrict__ x, const float* __restrict__ W_edge,
    const float* __restrict__ b_edge,
    const int* __restrict__ senders, const int* __restrict__ receivers,
    _Float16* __restrict__ y, float* __restrict__ z,
    unsigned int* __restrict__ table, unsigned int* __restrict__ bucketData,
    int N, int E, int NB)
{
    __shared__ unsigned int S[3200];   // bin only: 12.8KB
    int t = threadIdx.x;
    int bid = (int)blockIdx.x;

    if (bid < NBIN) {
        // ---------------- bin ----------------
        int* lcnt   = (int*)S;              // [NBP] histogram, then cursor
        int* lstart = (int*)S + NBP;        // [NBP] exclusive start
        unsigned int* stag = S + 2 * NBP;   // [CHUNK_STRIDE] sorted records

        int chunk = ((E + NBIN - 1) / NBIN + 1) & ~1;  // 1564 (even)
        int e0 = bid * chunk;
        int e1 = min(E, e0 + chunk);
        int nrec = max(0, e1 - e0);

        for (int i = t; i < NBP; i += 256) lcnt[i] = 0;
        __syncthreads();

        // paired edge loads (8B-aligned since e0 even) + stash + histogram
        unsigned int recs[8];
        const int2* s2 = (const int2*)(senders + e0);
        const int2* r2 = (const int2*)(receivers + e0);
#pragma unroll
        for (int i = 0; i < 4; ++i) {
            int p = t + i * 256;            // pair index
            int e = e0 + 2 * p;
            if (e + 1 < e1) {
                int2 sv = s2[p];
                int2 rv = r2[p];
                recs[2 * i]     = ((unsigned int)rv.x << 16) | (unsigned int)sv.x;
                recs[2 * i + 1] = ((unsigned int)rv.y << 16) | (unsigned int)sv.y;
                atomicAdd(&lcnt[(unsigned int)rv.x >> BSHIFT], 1);
                atomicAdd(&lcnt[(unsigned int)rv.y >> BSHIFT], 1);
            } else if (e < e1) {            // lone tail edge (odd count)
                unsigned int r = (unsigned int)receivers[e];
                unsigned int s = (unsigned int)senders[e];
                recs[2 * i]     = (r << 16) | s;
                recs[2 * i + 1] = 0xFFFFFFFFu;
                atomicAdd(&lcnt[r >> BSHIFT], 1);
            } else {
                recs[2 * i] = recs[2 * i + 1] = 0xFFFFFFFFu;
            }
        }
        __syncthreads();

        // exclusive scan of lcnt[0..NBP) -> lstart
        {
            int i0 = t * 4;
            int a0 = (i0 + 0 < NBP) ? lcnt[i0 + 0] : 0;
            int a1 = (i0 + 1 < NBP) ? lcnt[i0 + 1] : 0;
            int a2 = (i0 + 2 < NBP) ? lcnt[i0 + 2] : 0;
            int a3 = (i0 + 3 < NBP) ? lcnt[i0 + 3] : 0;
            int tsum = a0 + a1 + a2 + a3;
            int lane = t & 63, w = t >> 6;
            int incl = tsum;
#pragma unroll
            for (int d = 1; d < 64; d <<= 1) {
                int u = __shfl_up(incl, d);
                if (lane >= d) incl += u;
            }
            __shared__ int wsum[4];
            if (lane == 63) wsum[w] = incl;
            __syncthreads();
            int base = 0;
            for (int j = 0; j < w; ++j) base += wsum[j];
            int excl = base + incl - tsum;
            if (i0 + 0 < NBP) lstart[i0 + 0] = excl;
            if (i0 + 1 < NBP) lstart[i0 + 1] = excl + a0;
            if (i0 + 2 < NBP) lstart[i0 + 2] = excl + a0 + a1;
            if (i0 + 3 < NBP) lstart[i0 + 3] = excl + a0 + a1 + a2;
        }
        __syncthreads();
        for (int i = t; i < NBP; i += 256) lcnt[i] = lstart[i];  // cursor
        __syncthreads();

        // place records into staging, sorted by bucket
#pragma unroll
        for (int i = 0; i < 8; ++i) {
            unsigned int rec = recs[i];
            if (rec != 0xFFFFFFFFu) {
                int bkt = (int)(rec >> (16 + BSHIFT));
                int pos = atomicAdd(&lcnt[bkt], 1);
                stag[pos] = (((rec >> 16) & (BNODES - 1)) << 16) | (rec & 0xFFFFu);
            }
        }
        __syncthreads();

        // uint2-coalesced flush + coalesced descriptor row
        unsigned int* dstC = bucketData + (long)bid * CHUNK_STRIDE;
        {
            int npair = nrec >> 1;
            const uint2* st2 = (const uint2*)stag;
            uint2* d2 = (uint2*)dstC;
            for (int i = t; i < npair; i += 256) d2[i] = st2[i];
            if (t == 0 && (nrec & 1)) dstC[nrec - 1] = stag[nrec - 1];
        }
        unsigned int* dstT = table + (long)bid * NBP;
        for (int i = t; i < NB; i += 256) {
            int st = lstart[i];
            dstT[i] = ((unsigned int)st << 16) | (unsigned int)(lcnt[i] - st);
        }
    } else {
        // ---------------- transform (MFMA, no LDS) ------------------------
        int tIdx = bid - NBIN;
        int lane = t & 63, wid = t >> 6;
        int mrow = lane & 15;               // A row / D col
        int kgrp = lane >> 4;               // 0..3
        int koff = kgrp * 8;

        // B fragments: [kstep][half] for wb (y) and wd=wt-wb (z)
        v8h fb[2][2], fd[2][2];
#pragma unroll
        for (int s = 0; s < 2; ++s) {
            int kb = s * 32 + koff;
#pragma unroll
            for (int h = 0; h < 2; ++h) {
                int n = h * 16 + mrow;
                v8h vb, vd;
#pragma unroll
                for (int j = 0; j < 8; ++j) {
                    float wt = W_edge[(kb + j) * NC + n];
                    float wb = W_edge[(NF + kb + j) * NC + n];
                    vb[j] = (_Float16)wb;
                    vd[j] = (_Float16)(wt - wb);
                }
                fb[s][h] = vb; fd[s][h] = vd;
            }
        }
        float be0 = b_edge[mrow];
        float be1 = b_edge[16 + mrow];

        long base = (long)tIdx * 256 + (long)wid * 64;
#pragma unroll 1
        for (int tile = 0; tile < 4; ++tile) {
            long nb = base + tile * 16;
            long row = nb + mrow; if (row > N - 1) row = N - 1;
            const float4* xr = (const float4*)(x + row * NF);

            v8h fa[2];
#pragma unroll
            for (int s = 0; s < 2; ++s) {
                float4 u0 = xr[(s * 32 + koff) >> 2];
                float4 u1 = xr[((s * 32 + koff) >> 2) + 1];
                v8h a;
                a[0] = (_Float16)u0.x; a[1] = (_Float16)u0.y;
                a[2] = (_Float16)u0.z; a[3] = (_Float16)u0.w;
                a[4] = (_Float16)u1.x; a[5] = (_Float16)u1.y;
                a[6] = (_Float16)u1.z; a[7] = (_Float16)u1.w;
                fa[s] = a;
            }
            v4f ay0 = {0.f,0.f,0.f,0.f}, ay1 = {0.f,0.f,0.f,0.f};
            v4f az0 = {0.f,0.f,0.f,0.f}, az1 = {0.f,0.f,0.f,0.f};
#pragma unroll
            for (int s = 0; s < 2; ++s) {
                ay0 = __builtin_amdgcn_mfma_f32_16x16x32_f16(fa[s], fb[s][0], ay0, 0, 0, 0);
                ay1 = __builtin_amdgcn_mfma_f32_16x16x32_f16(fa[s], fb[s][1], ay1, 0, 0, 0);
                az0 = __builtin_amdgcn_mfma_f32_16x16x32_f16(fa[s], fd[s][0], az0, 0, 0, 0);
                az1 = __builtin_amdgcn_mfma_f32_16x16x32_f16(fa[s], fd[s][1], az1, 0, 0, 0);
            }
            // D layout: col = lane&15 (=channel), row = kgrp*4 + r (=node)
#pragma unroll
            for (int r = 0; r < 4; ++r) {
                long n = nb + kgrp * 4 + r;
                if (n < N) {
                    y[(n << 5) + mrow]      = (_Float16)ay0[r];
                    y[(n << 5) + 16 + mrow] = (_Float16)ay1[r];
                    z[(n << 5) + mrow]      = az0[r] + be0;
                    z[(n << 5) + 16 + mrow] = az1[r] + be1;
                }
            }
        }
    }
}

// ---------------------------------------------------------------------------
// Kernel B: per-bucket. XCD-chunked bucket swizzle. Row-major descriptor read
// -> 512-scan -> TWO-PASS DIRECT-FROM-GLOBAL histogram + scatter (raw[] LDS
// round-trip removed; second read hits L1/L2) -> register gather-sum (f16 y)
// -> BN -> head -> sigmoid.
// ---------------------------------------------------------------------------
__global__ __launch_bounds__(512) void aggregate_finalize_kernel(
    const unsigned int* __restrict__ table,
    const unsigned int* __restrict__ bucketData,
    const _Float16* __restrict__ y, const float* __restrict__ z,
    const float* __restrict__ gamma, const float* __restrict__ beta,
    const float* __restrict__ mean, const float* __restrict__ var,
    const float* __restrict__ W1, const float* __restrict__ b1,
    const float* __restrict__ W2, const float* __restrict__ b2,
    float* __restrict__ out, int N)
{
    __shared__ unsigned short srec[CAPR];  // senders sorted by nl
    __shared__ int   segsum[8];
    __shared__ int   cnt64[BNODES];        // nl histogram, then cursor
    __shared__ int   off[BNODES + 1];
    __shared__ float hL[BNODES * (NC + 1)];
    __shared__ float redL[BNODES][17];
    __shared__ float w1s[NC * 16];
    __shared__ float scale_s[NC], shift_s[NC], w2s[16], b1s[16];

    int t = threadIdx.x;
    // bijective XCD-chunked swizzle (m204): XCD x gets a contiguous b-range
    int b;
    {
        int orig = (int)blockIdx.x;
        int nwg = (int)gridDim.x;
        int q = nwg >> 3, r = nwg & 7;
        int xcd = orig & 7, o8 = orig >> 3;
        b = (xcd < r ? xcd * (q + 1) : r * (q + 1) + (xcd - r) * q) + o8;
    }

    if (t < NC) {
        float sc = gamma[t] * rsqrtf(var[t] + BN_EPS);
        scale_s[t] = sc;
        shift_s[t] = beta[t] - mean[t] * sc;
    }
    if (t < NC * 16) w1s[t] = W1[t];
    if (t >= 64 && t < 80) { w2s[t - 64] = W2[t - 64]; b1s[t - 64] = b1[t - 64]; }
    if (t >= 128 && t < 128 + BNODES) cnt64[t - 128] = 0;

    // descriptor read (row-major table; line-shared across neighbor buckets)
    unsigned int d = table[(long)t * NBP + b];
    int ct = (int)(d & 0xFFFFu);
    int st = (int)(d >> 16);
    __syncthreads();   // cnt64 zeroed before histogram

    const unsigned int* src = bucketData + (long)t * CHUNK_STRIDE + st;

    // pass 1: nl-histogram straight from global (lines become L1/L2-hot)
    for (int k = 0; k < ct; ++k)
        atomicAdd(&cnt64[src[k] >> 16], 1);
    __syncthreads();

    // exclusive scan over 64 keys (single wave64)
    if (t < BNODES) {
        int v = cnt64[t];
        int incl2 = v;
#pragma unroll
        for (int dd = 1; dd < 64; dd <<= 1) {
            int u = __shfl_up(incl2, dd);
            if ((t & 63) >= dd) incl2 += u;
        }
        off[t] = incl2 - v;
        cnt64[t] = incl2 - v;            // cursor
        if (t == BNODES - 1) off[BNODES] = incl2;
    }
    __syncthreads();

    // pass 2: scatter senders into nl-sorted srec (cache-hot re-read)
    for (int k = 0; k < ct; ++k) {
        unsigned int rv = src[k];
        int nl = (int)(rv >> 16);
        int pos = atomicAdd(&cnt64[nl], 1);
        if (pos < CAPR) srec[pos] = (unsigned short)(rv & 0xFFFFu);
    }
    __syncthreads();

    // gather-sum in registers: group g handles nodes 4g..4g+3, 4-wide unroll
    long n0 = (long)b << BSHIFT;
    int g = t >> 5, c = t & 31;
    const _Float16* yc = y + c;
#pragma unroll
    for (int j = 0; j < 4; ++j) {
        int nl = (g << 2) | j;
        int o0 = min(off[nl], CAPR), o1 = min(off[nl + 1], CAPR);
        float acc = 0.f;
        int k = o0;
        for (; k + 4 <= o1; k += 4) {
            int s0 = srec[k], s1 = srec[k + 1], s2 = srec[k + 2], s3 = srec[k + 3];
            float a0 = (float)yc[s0 << 5];
            float a1 = (float)yc[s1 << 5];
            float a2 = (float)yc[s2 << 5];
            float a3 = (float)yc[s3 << 5];
            acc += (a0 + a1) + (a2 + a3);
        }
        for (; k < o1; ++k) acc += (float)yc[(int)srec[k] << 5];
        float hb = 0.f;
        long n = n0 + nl;
        if (n < N) {
            float h = (float)(o1 - o0) * z[(n << 5) + c] + acc;
            hb = fmaf(h, scale_s[c], shift_s[c]);
        }
        hL[nl * (NC + 1) + c] = hb;
    }
    __syncthreads();

    // head: 64 nodes x 16 hidden = 1024 items over 512 threads
    for (int i = t; i < BNODES * 16; i += 512) {
        int nd = i >> 4, k = i & 15;
        float a = b1s[k];
#pragma unroll
        for (int cc = 0; cc < NC; ++cc)
            a = fmaf(hL[nd * (NC + 1) + cc], w1s[cc * 16 + k], a);
        redL[nd][k] = fmaxf(a, 0.f) * w2s[k];
    }
    __syncthreads();

    if (t < BNODES) {
        long n = n0 + t;
        if (n < N) {
            float o = b2[0];
#pragma unroll
            for (int k = 0; k < 16; ++k) o += redL[t][k];
            out[n] = 1.f / (1.f + expf(-o));
        }
    }
}

// ---------------------------------------------------------------------------
extern "C" void kernel_launch(void* const* d_in, const int* in_sizes, int n_in,
                              void* d_out, int out_size, void* d_ws, size_t ws_size,
                              hipStream_t stream)
{
    const float* x         = (const float*)d_in[0];
    const int*   senders   = (const int*)  d_in[1];
    const int*   receivers = (const int*)  d_in[2];
    const float* W_edge    = (const float*)d_in[3];
    const float* b_edge    = (const float*)d_in[4];
    const float* gamma     = (const float*)d_in[5];
    const float* beta      = (const float*)d_in[6];
    const float* mov_mean  = (const float*)d_in[7];
    const float* mov_var   = (const float*)d_in[8];
    const float* W1        = (const float*)d_in[9];
    const float* b1        = (const float*)d_in[10];
    const float* W2        = (const float*)d_in[11];
    const float* b2        = (const float*)d_in[12];
    float* out = (float*)d_out;

    const int N = in_sizes[0] / NF;   // 50000
    const int E = in_sizes[1];        // 800000
    const int NB = (N + BNODES - 1) >> BSHIFT;   // 782
    const int TB = (N + 255) / 256;              // 196 MFMA transform blocks

    // ws layout: y[N*32]f16 | z[N*32]f | table[NBIN*NBP]u32 | bucketData
    _Float16* y         = (_Float16*)d_ws;
    float* z            = (float*)(y + (long)N * NC);
    unsigned int* table = (unsigned int*)(z + (long)N * NC);
    unsigned int* bucketData = table + (long)NBIN * NBP;

    prep_kernel<<<NBIN + TB, 256, 0, stream>>>(
        x, W_edge, b_edge, senders, receivers, y, z, table, bucketData,
        N, E, NB);

    aggregate_finalize_kernel<<<NB, 512, 0, stream>>>(
        table, bucketData, y, z, gamma, beta, mov_mean, mov_var,
        W1, b1, W2, b2, out, N);
}

// Round 24
// 41.064 us; speedup vs baseline: 1.0727x; 1.0727x over previous
//
#include <hip/hip_runtime.h>
#include <math.h>

// Problem constants (from reference): N=50000, F=64, E=800000, C=32
#define NF 64
#define NC 32
#define BN_EPS 1e-3f

#define BSHIFT 6                 // 64 receiver-nodes per bucket
#define BNODES 64
#define NBP 800                  // padded bucket count (>= 782)
#define NBIN 512                 // bin blocks / chunks
#define EPT 7                    // edges per thread in bin (7*256=1792 >= 1563)
#define CHUNK_STRIDE 1600        // u32 slots per bin chunk (>= 1563)
#define CAPR 1408                // max records per bucket (mean 1023, +12 sigma)

typedef _Float16 v8h __attribute__((ext_vector_type(8)));
typedef float    v4f __attribute__((ext_vector_type(4)));

// ---------------------------------------------------------------------------
// Fused kernel A. blockIdx [0,NBIN) = bin, [NBIN, NBIN+TB) = transform.
// (R21 winner, verbatim.)
//
// Transform (MFMA): one wave = 4 tiles of 16 nodes (256 nodes/block, TB=196).
//   y = x@Wb (f16), z = x@(Wt-Wb)+b (f32) via v_mfma_f32_16x16x32_f16.
//   D-layout (m89-verified): col=lane&15, row=(lane>>4)*4+reg. No LDS.
// Bin: single pass over 1563-edge chunk -> register stash -> LDS histogram
//   over 782 buckets -> LDS scan -> LDS staging sorted by bucket -> coalesced
//   flush + coalesced (row-major) descriptor row.
// ---------------------------------------------------------------------------
__global__ __launch_bounds__(256) void prep_kernel(
    const float* __restrict__ x, const float* __restrict__ W_edge,
    const float* __restrict__ b_edge,
    const int* __restrict__ senders, const int* __restrict__ receivers,
    _Float16* __restrict__ y, float* __restrict__ z,
    unsigned int* __restrict__ table, unsigned int* __restrict__ bucketData,
    int N, int E, int NB)
{
    __shared__ unsigned int S[3200];   // bin only: 12.8KB
    int t = threadIdx.x;
    int bid = (int)blockIdx.x;

    if (bid < NBIN) {
        // ---------------- bin ----------------
        int* lcnt   = (int*)S;              // [NBP] histogram, then cursor
        int* lstart = (int*)S + NBP;        // [NBP] exclusive start
        unsigned int* stag = S + 2 * NBP;   // [CHUNK_STRIDE] sorted records

        int chunk = (E + NBIN - 1) / NBIN;  // 1563
        int e0 = bid * chunk;
        int e1 = min(E, e0 + chunk);
        int nrec = max(0, e1 - e0);

        for (int i = t; i < NBP; i += 256) lcnt[i] = 0;
        __syncthreads();

        unsigned int recs[EPT];
#pragma unroll
        for (int i = 0; i < EPT; ++i) {
            int e = e0 + t + i * 256;
            if (e < e1) {
                unsigned int r = (unsigned int)receivers[e];
                unsigned int s = (unsigned int)senders[e];   // < 65536
                recs[i] = (r << 16) | s;
                atomicAdd(&lcnt[r >> BSHIFT], 1);
            } else {
                recs[i] = 0xFFFFFFFFu;      // r=0xFFFF impossible (N<65536)
            }
        }
        __syncthreads();

        // exclusive scan of lcnt[0..NBP) -> lstart
        {
            int i0 = t * 4;
            int a0 = (i0 + 0 < NBP) ? lcnt[i0 + 0] : 0;
            int a1 = (i0 + 1 < NBP) ? lcnt[i0 + 1] : 0;
            int a2 = (i0 + 2 < NBP) ? lcnt[i0 + 2] : 0;
            int a3 = (i0 + 3 < NBP) ? lcnt[i0 + 3] : 0;
            int tsum = a0 + a1 + a2 + a3;
            int lane = t & 63, w = t >> 6;
            int incl = tsum;
#pragma unroll
            for (int d = 1; d < 64; d <<= 1) {
                int u = __shfl_up(incl, d);
                if (lane >= d) incl += u;
            }
            __shared__ int wsum[4];
            if (lane == 63) wsum[w] = incl;
            __syncthreads();
            int base = 0;
            for (int j = 0; j < w; ++j) base += wsum[j];
            int excl = base + incl - tsum;
            if (i0 + 0 < NBP) lstart[i0 + 0] = excl;
            if (i0 + 1 < NBP) lstart[i0 + 1] = excl + a0;
            if (i0 + 2 < NBP) lstart[i0 + 2] = excl + a0 + a1;
            if (i0 + 3 < NBP) lstart[i0 + 3] = excl + a0 + a1 + a2;
        }
        __syncthreads();
        for (int i = t; i < NBP; i += 256) lcnt[i] = lstart[i];  // cursor
        __syncthreads();

        // place records into staging, sorted by bucket
#pragma unroll
        for (int i = 0; i < EPT; ++i) {
            unsigned int rec = recs[i];
            if (rec != 0xFFFFFFFFu) {
                int bkt = (int)(rec >> (16 + BSHIFT));
                int pos = atomicAdd(&lcnt[bkt], 1);
                stag[pos] = (((rec >> 16) & (BNODES - 1)) << 16) | (rec & 0xFFFFu);
            }
        }
        __syncthreads();

        // coalesced flush + coalesced (row-major) descriptor stores
        unsigned int* dstC = bucketData + (long)bid * CHUNK_STRIDE;
        for (int i = t; i < nrec; i += 256) dstC[i] = stag[i];
        unsigned int* dstT = table + (long)bid * NBP;
        for (int i = t; i < NB; i += 256) {
            int st = lstart[i];
            dstT[i] = ((unsigned int)st << 16) | (unsigned int)(lcnt[i] - st);
        }
    } else {
        // ---------------- transform (MFMA, no LDS) ------------------------
        int tIdx = bid - NBIN;
        int lane = t & 63, wid = t >> 6;
        int mrow = lane & 15;               // A row / D col
        int kgrp = lane >> 4;               // 0..3
        int koff = kgrp * 8;

        // B fragments: [kstep][half] for wb (y) and wd=wt-wb (z)
        v8h fb[2][2], fd[2][2];
#pragma unroll
        for (int s = 0; s < 2; ++s) {
            int kb = s * 32 + koff;
#pragma unroll
            for (int h = 0; h < 2; ++h) {
                int n = h * 16 + mrow;
                v8h vb, vd;
#pragma unroll
                for (int j = 0; j < 8; ++j) {
                    float wt = W_edge[(kb + j) * NC + n];
                    float wb = W_edge[(NF + kb + j) * NC + n];
                    vb[j] = (_Float16)wb;
                    vd[j] = (_Float16)(wt - wb);
                }
                fb[s][h] = vb; fd[s][h] = vd;
            }
        }
        float be0 = b_edge[mrow];
        float be1 = b_edge[16 + mrow];

        long base = (long)tIdx * 256 + (long)wid * 64;
#pragma unroll 1
        for (int tile = 0; tile < 4; ++tile) {
            long nb = base + tile * 16;
            long row = nb + mrow; if (row > N - 1) row = N - 1;
            const float4* xr = (const float4*)(x + row * NF);

            v8h fa[2];
#pragma unroll
            for (int s = 0; s < 2; ++s) {
                float4 u0 = xr[(s * 32 + koff) >> 2];
                float4 u1 = xr[((s * 32 + koff) >> 2) + 1];
                v8h a;
                a[0] = (_Float16)u0.x; a[1] = (_Float16)u0.y;
                a[2] = (_Float16)u0.z; a[3] = (_Float16)u0.w;
                a[4] = (_Float16)u1.x; a[5] = (_Float16)u1.y;
                a[6] = (_Float16)u1.z; a[7] = (_Float16)u1.w;
                fa[s] = a;
            }
            v4f ay0 = {0.f,0.f,0.f,0.f}, ay1 = {0.f,0.f,0.f,0.f};
            v4f az0 = {0.f,0.f,0.f,0.f}, az1 = {0.f,0.f,0.f,0.f};
#pragma unroll
            for (int s = 0; s < 2; ++s) {
                ay0 = __builtin_amdgcn_mfma_f32_16x16x32_f16(fa[s], fb[s][0], ay0, 0, 0, 0);
                ay1 = __builtin_amdgcn_mfma_f32_16x16x32_f16(fa[s], fb[s][1], ay1, 0, 0, 0);
                az0 = __builtin_amdgcn_mfma_f32_16x16x32_f16(fa[s], fd[s][0], az0, 0, 0, 0);
                az1 = __builtin_amdgcn_mfma_f32_16x16x32_f16(fa[s], fd[s][1], az1, 0, 0, 0);
            }
            // D layout: col = lane&15 (=channel), row = kgrp*4 + r (=node)
#pragma unroll
            for (int r = 0; r < 4; ++r) {
                long n = nb + kgrp * 4 + r;
                if (n < N) {
                    y[(n << 5) + mrow]      = (_Float16)ay0[r];
                    y[(n << 5) + 16 + mrow] = (_Float16)ay1[r];
                    z[(n << 5) + mrow]      = az0[r] + be0;
                    z[(n << 5) + 16 + mrow] = az1[r] + be1;
                }
            }
        }
    }
}

// ---------------------------------------------------------------------------
// Kernel B: per-bucket. XCD-chunked bucket swizzle (makes the row-major
// descriptor reads L2-local). Descriptor read -> 512-scan -> segment copy
// with folded nl-histogram -> 64-key sort -> register gather-sum (f16 y) ->
// BN -> head -> sigmoid.
// ---------------------------------------------------------------------------
__global__ __launch_bounds__(512) void aggregate_finalize_kernel(
    const unsigned int* __restrict__ table,
    const unsigned int* __restrict__ bucketData,
    const _Float16* __restrict__ y, const float* __restrict__ z,
    const float* __restrict__ gamma, const float* __restrict__ beta,
    const float* __restrict__ mean, const float* __restrict__ var,
    const float* __restrict__ W1, const float* __restrict__ b1,
    const float* __restrict__ W2, const float* __restrict__ b2,
    float* __restrict__ out, int N)
{
    __shared__ unsigned int raw[CAPR];     // records (nl<<16 | s); later redL
    __shared__ unsigned short srec[CAPR];  // senders sorted by nl
    __shared__ int   segsum[8];
    __shared__ int   cnt64[BNODES];        // nl histogram, then cursor
    __shared__ int   off[BNODES + 1];
    __shared__ float hL[BNODES * (NC + 1)];
    __shared__ float w1s[NC * 16];
    __shared__ float scale_s[NC], shift_s[NC], w2s[16], b1s[16];
    float (*redL)[17] = reinterpret_cast<float(*)[17]>(raw);  // alias dead raw

    int t = threadIdx.x;
    // bijective XCD-chunked swizzle (m204): XCD x gets a contiguous b-range
    int b;
    {
        int orig = (int)blockIdx.x;
        int nwg = (int)gridDim.x;
        int q = nwg >> 3, r = nwg & 7;
        int xcd = orig & 7, o8 = orig >> 3;
        b = (xcd < r ? xcd * (q + 1) : r * (q + 1) + (xcd - r) * q) + o8;
    }

    if (t < NC) {
        float sc = gamma[t] * rsqrtf(var[t] + BN_EPS);
        scale_s[t] = sc;
        shift_s[t] = beta[t] - mean[t] * sc;
    }
    if (t < NC * 16) w1s[t] = W1[t];
    if (t >= 64 && t < 80) { w2s[t - 64] = W2[t - 64]; b1s[t - 64] = b1[t - 64]; }
    if (t >= 128 && t < 128 + BNODES) cnt64[t - 128] = 0;

    // descriptor read (row-major table; line-shared across neighbor buckets)
    unsigned int d = table[(long)t * NBP + b];
    int ct = (int)(d & 0xFFFFu);
    int st = (int)(d >> 16);
    int lane = t & 63, w = t >> 6;
    int incl = ct;
#pragma unroll
    for (int dd = 1; dd < 64; dd <<= 1) {
        int u = __shfl_up(incl, dd);
        if (lane >= dd) incl += u;
    }
    if (lane == 63) segsum[w] = incl;
    __syncthreads();
    int base = 0, tot = 0;
#pragma unroll
    for (int j = 0; j < 8; ++j) {
        int v = segsum[j];
        if (j < w) base += v;
        tot += v;
    }
    int dst = base + incl - ct;
    if (tot > CAPR) tot = CAPR;

    // copy my contiguous segment into raw[] + fold nl-histogram
    {
        const unsigned int* src = bucketData + (long)t * CHUNK_STRIDE + st;
        for (int k = 0; k < ct; ++k) {
            int p = dst + k;
            if (p < CAPR) {
                unsigned int rv = src[k];
                raw[p] = rv;
                atomicAdd(&cnt64[rv >> 16], 1);
            }
        }
    }
    __syncthreads();

    // exclusive scan over 64 keys (single wave64)
    if (t < BNODES) {
        int v = cnt64[t];
        int incl2 = v;
#pragma unroll
        for (int dd = 1; dd < 64; dd <<= 1) {
            int u = __shfl_up(incl2, dd);
            if ((t & 63) >= dd) incl2 += u;
        }
        off[t] = incl2 - v;
        cnt64[t] = incl2 - v;            // cursor
        if (t == BNODES - 1) off[BNODES] = incl2;
    }
    __syncthreads();

    // scatter senders into nl-sorted order
    for (int k = t; k < tot; k += 512) {
        unsigned int rv = raw[k];
        int nl = (int)(rv >> 16);
        int pos = atomicAdd(&cnt64[nl], 1);
        srec[pos] = (unsigned short)(rv & 0xFFFFu);
    }
    __syncthreads();

    // gather-sum in registers: group g handles nodes 4g..4g+3, 4-wide unroll
    long n0 = (long)b << BSHIFT;
    int g = t >> 5, c = t & 31;
    const _Float16* yc = y + c;
#pragma unroll
    for (int j = 0; j < 4; ++j) {
        int nl = (g << 2) | j;
        int o0 = off[nl], o1 = off[nl + 1];
        float acc = 0.f;
        int k = o0;
        for (; k + 4 <= o1; k += 4) {
            int s0 = srec[k], s1 = srec[k + 1], s2 = srec[k + 2], s3 = srec[k + 3];
            float a0 = (float)yc[s0 << 5];
            float a1 = (float)yc[s1 << 5];
            float a2 = (float)yc[s2 << 5];
            float a3 = (float)yc[s3 << 5];
            acc += (a0 + a1) + (a2 + a3);
        }
        for (; k < o1; ++k) acc += (float)yc[(int)srec[k] << 5];
        float hb = 0.f;
        long n = n0 + nl;
        if (n < N) {
            float h = (float)(o1 - o0) * z[(n << 5) + c] + acc;
            hb = fmaf(h, scale_s[c], shift_s[c]);
        }
        hL[nl * (NC + 1) + c] = hb;
    }
    __syncthreads();

    // head: 64 nodes x 16 hidden = 1024 items over 512 threads
    for (int i = t; i < BNODES * 16; i += 512) {
        int nd = i >> 4, k = i & 15;
        float a = b1s[k];
#pragma unroll
        for (int cc = 0; cc < NC; ++cc)
            a = fmaf(hL[nd * (NC + 1) + cc], w1s[cc * 16 + k], a);
        redL[nd][k] = fmaxf(a, 0.f) * w2s[k];
    }
    __syncthreads();

    if (t < BNODES) {
        long n = n0 + t;
        if (n < N) {
            float o = b2[0];
#pragma unroll
            for (int k = 0; k < 16; ++k) o += redL[t][k];
            out[n] = 1.f / (1.f + expf(-o));
        }
    }
}

// ---------------------------------------------------------------------------
extern "C" void kernel_launch(void* const* d_in, const int* in_sizes, int n_in,
                              void* d_out, int out_size, void* d_ws, size_t ws_size,
                              hipStream_t stream)
{
    const float* x         = (const float*)d_in[0];
    const int*   senders   = (const int*)  d_in[1];
    const int*   receivers = (const int*)  d_in[2];
    const float* W_edge    = (const float*)d_in[3];
    const float* b_edge    = (const float*)d_in[4];
    const float* gamma     = (const float*)d_in[5];
    const float* beta      = (const float*)d_in[6];
    const float* mov_mean  = (const float*)d_in[7];
    const float* mov_var   = (const float*)d_in[8];
    const float* W1        = (const float*)d_in[9];
    const float* b1        = (const float*)d_in[10];
    const float* W2        = (const float*)d_in[11];
    const float* b2        = (const float*)d_in[12];
    float* out = (float*)d_out;

    const int N = in_sizes[0] / NF;   // 50000
    const int E = in_sizes[1];        // 800000
    const int NB = (N + BNODES - 1) >> BSHIFT;   // 782
    const int TB = (N + 255) / 256;              // 196 MFMA transform blocks

    // ws layout: y[N*32]f16 | z[N*32]f | table[NBIN*NBP]u32 | bucketData
    _Float16* y         = (_Float16*)d_ws;
    float* z            = (float*)(y + (long)N * NC);
    unsigned int* table = (unsigned int*)(z + (long)N * NC);
    unsigned int* bucketData = table + (long)NBIN * NBP;

    prep_kernel<<<NBIN + TB, 256, 0, stream>>>(
        x, W_edge, b_edge, senders, receivers, y, z, table, bucketData,
        N, E, NB);

    aggregate_finalize_kernel<<<NB, 512, 0, stream>>>(
        table, bucketData, y, z, gamma, beta, mov_mean, mov_var,
        W1, b1, W2, b2, out, N);
}